// Round 7
// baseline (347.294 us; speedup 1.0000x reference)
//
#include <hip/hip_runtime.h>
#include <hip/hip_bf16.h>
#include <stdint.h>

// Problem constants: B=4, S=2048, D_MODEL=1024, H=16, Dk=64
#define HN 16
#define DMODEL 1024
#define DKH 64
#define SEQ 2048

typedef __attribute__((ext_vector_type(8))) short short8v;   // 8 bf16
typedef __attribute__((ext_vector_type(4))) short short4v;   // 4 bf16
typedef __attribute__((ext_vector_type(4))) float f32x4;

__device__ __forceinline__ short bfc(float x) {
    __hip_bfloat16 h = __float2bfloat16(x);   // hardware RNE cvt
    return *reinterpret_cast<short*>(&h);
}

// async global->LDS, 16B/lane; LDS dest = wave-uniform base + lane*16 (we pass per-thread base+t*16)
__device__ __forceinline__ void gll16(const void* g, void* l) {
    __builtin_amdgcn_global_load_lds(
        (const __attribute__((address_space(1))) unsigned int*)g,
        (__attribute__((address_space(3))) unsigned int*)l, 16, 0, 0);
}

// ---------------- weight cvt: 4 weights in one launch (grid.z) ----------------
__global__ void cvtw_kernel(const float* __restrict__ w0, const float* __restrict__ w1,
                            const float* __restrict__ w2, const float* __restrict__ w3,
                            short* __restrict__ dst, float scale0) {
    const int z = blockIdx.z;
    const float* src = z == 0 ? w0 : z == 1 ? w1 : z == 2 ? w2 : w3;
    short* d = dst + ((size_t)z << 20);
    const float scale = (z == 0) ? scale0 : 1.f;
    const int i = blockIdx.x * blockDim.x + threadIdx.x;
    const float4 v0 = ((const float4*)src)[i * 2];
    const float4 v1 = ((const float4*)src)[i * 2 + 1];
    short8v o;
    o[0] = bfc(v0.x * scale); o[1] = bfc(v0.y * scale);
    o[2] = bfc(v0.z * scale); o[3] = bfc(v0.w * scale);
    o[4] = bfc(v1.x * scale); o[5] = bfc(v1.y * scale);
    o[6] = bfc(v1.z * scale); o[7] = bfc(v1.w * scale);
    ((short8v*)d)[i] = o;
}

// ---------------- projection GEMM (dbuf, fused fp32->bf16 A-staging) ----------------
// Flat grid 1536, XCD panel swizzle: all 8 n-blocks of an (m,z) panel land on one XCD
// (ids ≡ c mod 8) -> A panel fetched once, reused from that XCD's L2.
// A: fp32 global, loaded to regs (coalesced 256B/16-lane rows), cvt'd, ds_write_b128
// into XOR-swizzled LDS (same pattern as reads: 0 conflicts measured).
// B: bf16 weights via gll16 with XOR pre-swizzled source. BK=64, dbuf, 1 barrier/step.
__global__ __launch_bounds__(256) void gemm_proj(
    const float* __restrict__ xq, const float* __restrict__ xk, const float* __restrict__ xv,
    const short* __restrict__ wb,
    const float* __restrict__ bq, const float* __restrict__ bk, const float* __restrict__ bv,
    short* __restrict__ qb, short* __restrict__ kb, short* __restrict__ vtb, float c1)
{
    constexpr int K = DMODEL;
    const int id = blockIdx.x;                 // 0..1535
    const int cx = id & 7, jj = id >> 3;       // cx = XCD slot
    const int P = cx * 24 + (jj >> 3);         // panel 0..191 (= z*64 + mpanel)
    const int nblk = jj & 7;
    const int z = P >> 6, mp = P & 63;
    const int m0 = mp * 128, n0 = nblk * 128;

    const float* A    = z == 0 ? xq : z == 1 ? xk : xv;
    const short* W    = wb + ((size_t)z << 20);
    const float* bias = z == 0 ? bq : z == 1 ? bk : bv;
    const float bscale = (z == 0) ? c1 : 1.f;

    __shared__ __align__(16) short As[2][8192];   // [128][64] per buf, XOR-swizzled content
    __shared__ __align__(16) short Bs[2][8192];
    const int t = threadIdx.x, lane = t & 63;
    const int w = t >> 6, wr = w >> 1, wc = w & 1;
    const int r16 = lane & 15, g = lane >> 4;

    f32x4 acc[4][4];
    #pragma unroll
    for (int i = 0; i < 4; ++i)
        #pragma unroll
        for (int j = 0; j < 4; ++j) { acc[i][j][0]=0.f; acc[i][j][1]=0.f; acc[i][j][2]=0.f; acc[i][j][3]=0.f; }

    // A staging coords: thread t, iter p: row = (t>>3)+32p, 16B-chunk = t&7 (p-invariant XOR)
    const int ar = t >> 3, ac = t & 7;
    const int axor = ((ac ^ (ar & 7)) * 8);               // swizzled chunk offset (shorts)
    const float* Asrc = A + (size_t)(m0 + ar) * K + ac * 8;
    const int aoff = ar * 64 + axor;                      // + p*2048 per iter
    // B staging: XOR pre-swizzled source
    const int sr = t >> 3, sx = ((t & 7) ^ (sr & 7)) * 8;
    const short* Bsrc = W + (size_t)(n0 + sr) * K + sx;

    // prologue: stage tile 0
    {
        #pragma unroll
        for (int q4 = 0; q4 < 4; ++q4)
            gll16(Bsrc + (size_t)(q4*32) * K, &Bs[0][0] + t*8 + q4*2048);
        #pragma unroll
        for (int p = 0; p < 4; ++p) {
            const float* s = Asrc + (size_t)(p*32) * K;
            float4 f0 = *(const float4*)s;
            float4 f1 = *(const float4*)(s + 4);
            short8v sv;
            sv[0]=bfc(f0.x); sv[1]=bfc(f0.y); sv[2]=bfc(f0.z); sv[3]=bfc(f0.w);
            sv[4]=bfc(f1.x); sv[5]=bfc(f1.y); sv[6]=bfc(f1.z); sv[7]=bfc(f1.w);
            *(short8v*)&As[0][aoff + p*2048] = sv;
        }
    }
    __syncthreads();

    int cur = 0;
    for (int kt = 0; kt < K; kt += 64) {
        const int nxt = cur ^ 1;
        const bool more = (kt + 64) < K;
        float4 fa[4][2];
        if (more) {
            #pragma unroll
            for (int p = 0; p < 4; ++p) {      // issue next-tile A loads early
                const float* s = Asrc + kt + 64 + (size_t)(p*32) * K;
                fa[p][0] = *(const float4*)s;
                fa[p][1] = *(const float4*)(s + 4);
            }
            #pragma unroll
            for (int q4 = 0; q4 < 4; ++q4)
                gll16(Bsrc + kt + 64 + (size_t)(q4*32) * K, &Bs[nxt][0] + t*8 + q4*2048);
        }
        const short* Ac = As[cur];
        const short* Bc = Bs[cur];
        #pragma unroll
        for (int kk = 0; kk < 2; ++kk) {
            short8v a[4], b[4];
            #pragma unroll
            for (int i = 0; i < 4; ++i)
                a[i] = *(const short8v*)&Ac[(wr*64 + i*16 + r16)*64 + (((kk*4 + g) ^ (r16 & 7)) * 8)];
            #pragma unroll
            for (int j = 0; j < 4; ++j)
                b[j] = *(const short8v*)&Bc[(wc*64 + j*16 + r16)*64 + (((kk*4 + g) ^ (r16 & 7)) * 8)];
            #pragma unroll
            for (int i = 0; i < 4; ++i)
                #pragma unroll
                for (int j = 0; j < 4; ++j)
                    acc[i][j] = __builtin_amdgcn_mfma_f32_16x16x32_bf16(a[i], b[j], acc[i][j], 0, 0, 0);
        }
        if (more) {
            #pragma unroll
            for (int p = 0; p < 4; ++p) {      // cvt + swizzled ds_write_b128 into nxt
                short8v sv;
                sv[0]=bfc(fa[p][0].x); sv[1]=bfc(fa[p][0].y); sv[2]=bfc(fa[p][0].z); sv[3]=bfc(fa[p][0].w);
                sv[4]=bfc(fa[p][1].x); sv[5]=bfc(fa[p][1].y); sv[6]=bfc(fa[p][1].z); sv[7]=bfc(fa[p][1].w);
                *(short8v*)&As[nxt][aoff + p*2048] = sv;
            }
        }
        __syncthreads();
        cur ^= 1;
    }

    // epilogue: D col = lane&15 (n-sub), row = 4*(lane>>4)+reg (m-sub)
    #pragma unroll
    for (int i = 0; i < 4; ++i) {
        const int mbase = m0 + wr*64 + i*16 + g*4;
        #pragma unroll
        for (int j = 0; j < 4; ++j) {
            const int n = n0 + wc*64 + j*16 + r16;
            const float bvv = bias[n] * bscale;
            const int h = n >> 6, d = n & 63;
            if (z < 2) {
                short* ob = (z == 0) ? qb : kb;
                #pragma unroll
                for (int r = 0; r < 4; ++r) {
                    const int m = mbase + r;
                    const int bb = m >> 11, s = m & 2047;
                    ob[(((size_t)(bb*HN + h)*SEQ + s) << 6) + d] = bfc(acc[i][j][r] + bvv);
                }
            } else {
                const int bb = mbase >> 11, s = mbase & 2047;
                const int blk = s & ~31, b4 = (s >> 2) & 7;
                const int sp = blk | ((((b4 & 3) << 1) | (b4 >> 2)) << 2);   // pi-permute
                short4v pk;
                #pragma unroll
                for (int r = 0; r < 4; ++r) pk[r] = bfc(acc[i][j][r] + bvv);
                *(short4v*)&vtb[((size_t)(bb*HN + h)*DKH + d)*SEQ + sp] = pk;
            }
        }
    }
}

// ---------------- attention (unchanged from round 5) ----------------
__global__ __launch_bounds__(256, 4) void attn_kernel(
    const short* __restrict__ Qb, const short* __restrict__ Kb,
    const short* __restrict__ Vt, short* __restrict__ Ob)
{
    __shared__ __align__(16) short Ks[2][4096];   // [64 kv][64 d] per buf, swizzled
    __shared__ __align__(16) short Vs[2][4096];   // [64 d][64 kv'] per buf, swizzled
    const int t = threadIdx.x, lane = t & 63, w = t >> 6;
    const int r16 = lane & 15, g = lane >> 4;

    const int bid = blockIdx.x + (blockIdx.y << 4);          // 0..1023
    const int wg  = (bid & 7) * 128 + (bid >> 3);            // bijective XCD remap
    const int qx  = wg & 15, bh = wg >> 4;

    const size_t hq = (size_t)bh * SEQ * DKH;
    const size_t hv = (size_t)bh * DKH * SEQ;
    const int q0 = qx * 128 + w * 32;

    short8v aq[2][2];
    #pragma unroll
    for (int qm = 0; qm < 2; ++qm)
        #pragma unroll
        for (int h2 = 0; h2 < 2; ++h2)
            aq[qm][h2] = *(const short8v*)(Qb + hq + (size_t)(q0 + qm*16 + r16)*DKH + h2*32 + g*8);

    short8v ones;
    #pragma unroll
    for (int j = 0; j < 8; ++j) ones[j] = (short)0x3F80;

    f32x4 o[2][4], ps[2];
    #pragma unroll
    for (int qm = 0; qm < 2; ++qm) {
        ps[qm][0]=0.f; ps[qm][1]=0.f; ps[qm][2]=0.f; ps[qm][3]=0.f;
        #pragma unroll
        for (int d = 0; d < 4; ++d) { o[qm][d][0]=0.f; o[qm][d][1]=0.f; o[qm][d][2]=0.f; o[qm][d][3]=0.f; }
    }
    const f32x4 zinit = {-4.f, -4.f, -4.f, -4.f};

    const int sr = t >> 3, sx = ((t & 7) ^ (sr & 7)) * 8;
    const short* Ksrc = Kb + hq + (size_t)sr * DKH + sx;
    const short* Vsrc = Vt + hv + (size_t)sr * SEQ + sx;
    const int l0 = t * 8, l1 = 2048 + t * 8;

    gll16(Ksrc,                    &Ks[0][l0]);
    gll16(Ksrc + (size_t)32*DKH,   &Ks[0][l1]);
    gll16(Vsrc,                    &Vs[0][l0]);
    gll16(Vsrc + (size_t)32*SEQ,   &Vs[0][l1]);
    __syncthreads();

    int cur = 0;
    for (int kv0 = 0; kv0 < SEQ; kv0 += 64) {
        if (kv0 + 64 < SEQ) {
            const int nxt = cur ^ 1;
            const int kn = kv0 + 64;
            gll16(Ksrc + (size_t)kn*DKH,        &Ks[nxt][l0]);
            gll16(Ksrc + (size_t)(kn+32)*DKH,   &Ks[nxt][l1]);
            gll16(Vsrc + kn,                    &Vs[nxt][l0]);
            gll16(Vsrc + (size_t)32*SEQ + kn,   &Vs[nxt][l1]);
        }
        const short* Kc = Ks[cur];
        const short* Vc = Vs[cur];

        short8v pa[2][2];
        #pragma unroll
        for (int s2 = 0; s2 < 4; ++s2) {
            const int krow = (s2*16 + r16) * 64;
            short8v ak0 = *(const short8v*)&Kc[krow + ((g       ^ (r16 & 7)) * 8)];
            short8v ak1 = *(const short8v*)&Kc[krow + (((4 + g) ^ (r16 & 7)) * 8)];
            #pragma unroll
            for (int qm = 0; qm < 2; ++qm) {
                f32x4 zz = __builtin_amdgcn_mfma_f32_16x16x32_bf16(ak0, aq[qm][0], zinit, 0, 0, 0);
                zz = __builtin_amdgcn_mfma_f32_16x16x32_bf16(ak1, aq[qm][1], zz, 0, 0, 0);
                pa[qm][s2 >> 1][(s2 & 1)*4 + 0] = bfc(__builtin_amdgcn_exp2f(zz[0]));
                pa[qm][s2 >> 1][(s2 & 1)*4 + 1] = bfc(__builtin_amdgcn_exp2f(zz[1]));
                pa[qm][s2 >> 1][(s2 & 1)*4 + 2] = bfc(__builtin_amdgcn_exp2f(zz[2]));
                pa[qm][s2 >> 1][(s2 & 1)*4 + 3] = bfc(__builtin_amdgcn_exp2f(zz[3]));
            }
        }
        #pragma unroll
        for (int kvh = 0; kvh < 2; ++kvh) {
            #pragma unroll
            for (int qm = 0; qm < 2; ++qm)
                ps[qm] = __builtin_amdgcn_mfma_f32_16x16x32_bf16(pa[qm][kvh], ones, ps[qm], 0, 0, 0);
            #pragma unroll
            for (int dblk = 0; dblk < 4; ++dblk) {
                short8v bvv = *(const short8v*)&Vc[(dblk*16 + r16)*64 + (((kvh*4 + g) ^ (r16 & 7)) * 8)];
                #pragma unroll
                for (int qm = 0; qm < 2; ++qm)
                    o[qm][dblk] = __builtin_amdgcn_mfma_f32_16x16x32_bf16(pa[qm][kvh], bvv, o[qm][dblk], 0, 0, 0);
            }
        }
        __syncthreads();
        cur ^= 1;
    }

    const int bb = bh >> 4, h = bh & 15;
    #pragma unroll
    for (int qm = 0; qm < 2; ++qm)
        #pragma unroll
        for (int r = 0; r < 4; ++r) {
            const float rp = 1.f / ps[qm][r];
            const int q = q0 + qm*16 + g*4 + r;
            #pragma unroll
            for (int dblk = 0; dblk < 4; ++dblk)
                Ob[(size_t)(bb*SEQ + q)*DMODEL + h*DKH + dblk*16 + r16] = bfc(o[qm][dblk][r] * rp);
        }
}

// ---------------- output GEMM (dbuf, XCD panel swizzle): out fp32 = Ain(bf16)*Wo^T + bo ----------------
__global__ __launch_bounds__(256) void gemm_out(
    const short* __restrict__ Ain, const short* __restrict__ W,
    const float* __restrict__ bias, float* __restrict__ Out)
{
    constexpr int K = DMODEL;
    const int id = blockIdx.x;                 // 0..511
    const int cx = id & 7, jj = id >> 3;
    const int mp = cx * 8 + (jj >> 3), nblk = jj & 7;   // panel = m-block on XCD cx
    const int m0 = mp * 128, n0 = nblk * 128;

    __shared__ __align__(16) short As[2][8192];
    __shared__ __align__(16) short Bs[2][8192];
    const int t = threadIdx.x, lane = t & 63;
    const int w = t >> 6, wr = w >> 1, wc = w & 1;
    const int r16 = lane & 15, g = lane >> 4;

    f32x4 acc[4][4];
    #pragma unroll
    for (int i = 0; i < 4; ++i)
        #pragma unroll
        for (int j = 0; j < 4; ++j) { acc[i][j][0]=0.f; acc[i][j][1]=0.f; acc[i][j][2]=0.f; acc[i][j][3]=0.f; }

    const int sr = t >> 3, sx = ((t & 7) ^ (sr & 7)) * 8;
    const short* Asrc = Ain + (size_t)(m0 + sr) * K + sx;
    const short* Bsrc = W   + (size_t)(n0 + sr) * K + sx;

    #pragma unroll
    for (int q4 = 0; q4 < 4; ++q4) {
        gll16(Asrc + (size_t)(q4*32) * K, &As[0][0] + t*8 + q4*2048);
        gll16(Bsrc + (size_t)(q4*32) * K, &Bs[0][0] + t*8 + q4*2048);
    }
    __syncthreads();

    int cur = 0;
    for (int kt = 0; kt < K; kt += 64) {
        if (kt + 64 < K) {
            const int nxt = cur ^ 1;
            #pragma unroll
            for (int q4 = 0; q4 < 4; ++q4) {
                gll16(Asrc + kt + 64 + (size_t)(q4*32) * K, &As[nxt][0] + t*8 + q4*2048);
                gll16(Bsrc + kt + 64 + (size_t)(q4*32) * K, &Bs[nxt][0] + t*8 + q4*2048);
            }
        }
        const short* Ac = As[cur];
        const short* Bc = Bs[cur];
        #pragma unroll
        for (int kk = 0; kk < 2; ++kk) {
            short8v a[4], b[4];
            #pragma unroll
            for (int i = 0; i < 4; ++i)
                a[i] = *(const short8v*)&Ac[(wr*64 + i*16 + r16)*64 + (((kk*4 + g) ^ (r16 & 7)) * 8)];
            #pragma unroll
            for (int j = 0; j < 4; ++j)
                b[j] = *(const short8v*)&Bc[(wc*64 + j*16 + r16)*64 + (((kk*4 + g) ^ (r16 & 7)) * 8)];
            #pragma unroll
            for (int i = 0; i < 4; ++i)
                #pragma unroll
                for (int j = 0; j < 4; ++j)
                    acc[i][j] = __builtin_amdgcn_mfma_f32_16x16x32_bf16(a[i], b[j], acc[i][j], 0, 0, 0);
        }
        __syncthreads();
        cur ^= 1;
    }

    #pragma unroll
    for (int i = 0; i < 4; ++i) {
        const int mbase = m0 + wr*64 + i*16 + g*4;
        #pragma unroll
        for (int j = 0; j < 4; ++j) {
            const int n = n0 + wc*64 + j*16 + r16;
            const float bvv = bias[n];
            #pragma unroll
            for (int r = 0; r < 4; ++r)
                Out[(size_t)(mbase + r)*DMODEL + n] = acc[i][j][r] + bvv;
        }
    }
}

extern "C" void kernel_launch(void* const* d_in, const int* in_sizes, int n_in,
                              void* d_out, int out_size, void* d_ws, size_t ws_size,
                              hipStream_t stream) {
    const float* query = (const float*)d_in[0];
    const float* key   = (const float*)d_in[1];
    const float* value = (const float*)d_in[2];
    const float* w_q = (const float*)d_in[3];
    const float* b_q = (const float*)d_in[4];
    const float* w_k = (const float*)d_in[5];
    const float* b_k = (const float*)d_in[6];
    const float* w_v = (const float*)d_in[7];
    const float* b_v = (const float*)d_in[8];
    const float* w_o = (const float*)d_in[9];
    const float* b_o = (const float*)d_in[10];

    const float C1 = 0.18033688011112043f;  // 0.125 * log2(e), folded into w_q/b_q

    // ws (bf16 elems), 36M = 72MB:
    short* ws  = (short*)d_ws;
    short* wb  = ws;                       // 4M shorts: q,k,v,o weights
    short* xo  = ws + (4u  << 20);         // attn out [B,S,D] bf16
    short* qb  = ws + (12u << 20);         // [B,H,S,Dk]
    short* kb  = ws + (20u << 20);
    short* vtb = ws + (28u << 20);         // [B,H,Dk,S], kv pi-permuted per 32-block

    cvtw_kernel<<<dim3(512, 1, 4), 256, 0, stream>>>(w_q, w_k, w_v, w_o, wb, C1);

    gemm_proj<<<1536, 256, 0, stream>>>(query, key, value, wb,
                                        b_q, b_k, b_v, qb, kb, vtb, C1);

    attn_kernel<<<dim3(16, 64), 256, 0, stream>>>(qb, kb, vtb, xo);

    gemm_out<<<512, 256, 0, stream>>>(xo, wb + (3u << 20), b_o, (float*)d_out);
}